// Round 3
// baseline (32.117 us; speedup 1.0000x reference)
//
#include <hip/hip_runtime.h>

typedef _Float16 h2 __attribute__((ext_vector_type(2)));
typedef _Float16 h8 __attribute__((ext_vector_type(8)));

#define RANK  16
#define GRIDP 128
#define BLOCK 256
#define NBLK  4096

union H8 { h8 v; h2 p[4]; };

__device__ __forceinline__ float fdot2(h2 a, h2 b, float c) {
#if __has_builtin(__builtin_amdgcn_fdot2)
    return __builtin_amdgcn_fdot2(a, b, c, false);
#else
    return (float)a.x * (float)b.x + (float)a.y * (float)b.y + c;
#endif
}

__global__ __launch_bounds__(BLOCK, 4) void pinn_lora_kernel(
    const float* __restrict__ x, const float* __restrict__ line,
    const float* __restrict__ W, float* __restrict__ out, int npts)
{
    // Chunked fp16 table: tab[a][c][g] holds ranks 8c..8c+7 of grid row g.
    // 16B entries at stride 16B -> bank-quad class = g & 7 (max spread for b128).
    __shared__ h8 tab[3][2][GRIDP];

    _Float16* t = (_Float16*)tab;
    for (int i = threadIdx.x; i < 3 * RANK * GRIDP; i += BLOCK) {
        int a = i >> 11;          // / (16*128)
        int r = (i >> 7) & 15;    // rank
        int g = i & 127;          // grid row
        int c = r >> 3;           // rank half
        t[((((a << 1) + c) << 7) + g) * 8 + (r & 7)] = (_Float16)line[i];
    }

    // W[3][16] f32 -> packed f16. Uniform addresses -> scalar loads, and the
    // packed values stay in SGPRs (v_dot2 allows one SGPR operand).
    h2 Wp[3][8];
#pragma unroll
    for (int o = 0; o < 3; ++o)
#pragma unroll
        for (int d = 0; d < 8; ++d) {
            Wp[o][d].x = (_Float16)W[o * 16 + 2 * d];
            Wp[o][d].y = (_Float16)W[o * 16 + 2 * d + 1];
        }

    __syncthreads();

    int tid    = blockIdx.x * BLOCK + threadIdx.x;
    int stride = gridDim.x * BLOCK;

    for (int p = tid; p < npts; p += stride) {
        // x layout [N][3]; axis a interpolates coord x[:, 2-a]
        float cx = x[3 * p + 0];
        float cy = x[3 * p + 1];
        float cz = x[3 * p + 2];
        float crd[3] = {cz, cy, cx};

        H8 prod0, prod1;
#pragma unroll
        for (int a = 0; a < 3; ++a) {
            float pos = fmaf(crd[a], 63.5f, 63.5f);
            int   i0  = (int)pos;                  // pos >= 0 -> trunc == floor
            i0 = (i0 > 126) ? 126 : i0;            // guard the top edge
            float w = pos - (float)i0;
            _Float16 wh = (_Float16)w;
            h2 w2; w2.x = wh; w2.y = wh;

            H8 A0, A1, B0, B1;
            A0.v = tab[a][0][i0];     // row i0,   ranks 0..7
            B0.v = tab[a][0][i0 + 1]; // row i0+1, ranks 0..7
            A1.v = tab[a][1][i0];     // row i0,   ranks 8..15
            B1.v = tab[a][1][i0 + 1]; // row i0+1, ranks 8..15

            H8 v0, v1;
#pragma unroll
            for (int j = 0; j < 4; ++j) {
                v0.p[j] = A0.p[j] + (B0.p[j] - A0.p[j]) * w2;
                v1.p[j] = A1.p[j] + (B1.p[j] - A1.p[j]) * w2;
            }
            if (a == 0) { prod0 = v0; prod1 = v1; }
            else {
#pragma unroll
                for (int j = 0; j < 4; ++j) {
                    prod0.p[j] *= v0.p[j];
                    prod1.p[j] *= v1.p[j];
                }
            }
        }

#pragma unroll
        for (int oo = 0; oo < 3; ++oo) {
            float acc = 0.f;
#pragma unroll
            for (int j = 0; j < 4; ++j) {
                acc = fdot2(prod0.p[j], Wp[oo][j],     acc);
                acc = fdot2(prod1.p[j], Wp[oo][j + 4], acc);
            }
            out[3 * p + oo] = acc;
        }
    }
}

extern "C" void kernel_launch(void* const* d_in, const int* in_sizes, int n_in,
                              void* d_out, int out_size, void* d_ws, size_t ws_size,
                              hipStream_t stream) {
    const float* x    = (const float*)d_in[0];   // [N,3] f32
    const float* line = (const float*)d_in[1];   // [3,16,128] f32
    const float* W    = (const float*)d_in[2];   // [3,16] f32
    float*       out  = (float*)d_out;           // [N,3] f32

    int npts = in_sizes[0] / 3;

    pinn_lora_kernel<<<NBLK, BLOCK, 0, stream>>>(x, line, W, out, npts);
}